// Round 1
// baseline (1633.980 us; speedup 1.0000x reference)
//
#include <hip/hip_runtime.h>
#include <math.h>

#define PP 22
#define HH 64
#define NL 4
#define NEDGE 21   // edges per row (P-1)

#define WAVE_SYNC() asm volatile("s_waitcnt lgkmcnt(0)" ::: "memory")

__device__ __forceinline__ float silu_f(float v) {
    return v / (1.0f + __expf(-v));
}

// load 21 broadcast floats from a 24-stride row of the transpose buffer
#define LOAD_ZROW(PTR) \
    float4 za = *(const float4*)((PTR));      \
    float4 zb = *(const float4*)((PTR) + 4);  \
    float4 zc = *(const float4*)((PTR) + 8);  \
    float4 zd = *(const float4*)((PTR) + 12); \
    float4 ze = *(const float4*)((PTR) + 16); \
    float zf = (PTR)[20];

#define FMA21(A, WV) \
    A[0]  += za.x * (WV); A[1]  += za.y * (WV); A[2]  += za.z * (WV); A[3]  += za.w * (WV); \
    A[4]  += zb.x * (WV); A[5]  += zb.y * (WV); A[6]  += zb.z * (WV); A[7]  += zb.w * (WV); \
    A[8]  += zc.x * (WV); A[9]  += zc.y * (WV); A[10] += zc.z * (WV); A[11] += zc.w * (WV); \
    A[12] += zd.x * (WV); A[13] += zd.y * (WV); A[14] += zd.z * (WV); A[15] += zd.w * (WV); \
    A[16] += ze.x * (WV); A[17] += ze.y * (WV); A[18] += ze.z * (WV); A[19] += ze.w * (WV); \
    A[20] += zf   * (WV);

__global__ __launch_bounds__(256) void egnn_kernel(
    const float* __restrict__ input, const float* __restrict__ timev,
    const float* __restrict__ emb_w, const float* __restrict__ emb_b,
    const float* __restrict__ edge_w1, const float* __restrict__ edge_b1,
    const float* __restrict__ edge_w2, const float* __restrict__ edge_b2,
    const float* __restrict__ node_w1, const float* __restrict__ node_b1,
    const float* __restrict__ node_w2, const float* __restrict__ node_b2,
    const float* __restrict__ cm_w1, const float* __restrict__ cm_b1, const float* __restrict__ cm_w2,
    const float* __restrict__ cc_w1, const float* __restrict__ cc_b1, const float* __restrict__ cc_w2,
    float* __restrict__ out)
{
    const int g    = blockIdx.x;
    const int tid  = threadIdx.x;
    const int w    = tid >> 6;     // wave id 0..3
    const int lane = tid & 63;

    __shared__ float sh[PP][HH];       // node features h
    __shared__ float sApre[PP][HH];    // h @ W1[0:64]   (+b1)
    __shared__ float sBpre[PP][HH];    // h @ W1[64:128]
    __shared__ float sSegEf[PP][HH];   // segment-sum of ef per row-node
    __shared__ float sx[PP][3];
    __shared__ float sx0[PP][3];
    __shared__ float sea[PP][NEDGE];   // edge_attr (fixed, from x0)
    __shared__ float sTr[PP][3];       // per-node coordinate update
    __shared__ float zt[4][HH][24];    // per-wave transpose buffer [k][e], stride 24
    __shared__ float scd[4][NEDGE][3]; // coord_diff per wave
    __shared__ float scr[4][NEDGE][3]; // normalized cross per wave
    __shared__ float smean[3];

    // ---- init: coords ----
    if (tid < PP * 3) {
        float v = input[g * (PP * 3) + tid];
        sx0[tid / 3][tid % 3] = v;
        sx [tid / 3][tid % 3] = v;
    }
    // ---- init: h = onehot(p) @ emb_w + t*emb_w[22] + emb_b ----
    {
        float tg = timev[g];
        for (int i = w; i < PP; i += 4) {
            sh[i][lane] = emb_w[i * HH + lane] + tg * emb_w[PP * HH + lane] + emb_b[lane];
        }
    }
    __syncthreads();
    // ---- edge_attr from x0 ----
    for (int e = tid; e < PP * NEDGE; e += 256) {
        int a = e / NEDGE, r = e % NEDGE;
        int b = (r < a) ? r : r + 1;
        float dx = sx0[a][0] - sx0[b][0];
        float dy = sx0[a][1] - sx0[b][1];
        float dz = sx0[a][2] - sx0[b][2];
        sea[a][r] = dx * dx + dy * dy + dz * dz;
    }
    __syncthreads();

    for (int l = 0; l < NL; ++l) {
        const float* W1  = edge_w1 + l * 130 * HH;
        const float* B1  = edge_b1 + l * HH;
        const float* W2  = edge_w2 + l * HH * HH;
        const float* B2  = edge_b2 + l * HH;
        const float* CM1 = cm_w1  + l * HH * HH;
        const float* CMB = cm_b1  + l * HH;
        const float* CM2 = cm_w2  + l * HH;
        const float* CC1 = cc_w1  + l * HH * HH;
        const float* CCB = cc_b1  + l * HH;
        const float* CC2 = cc_w2  + l * HH;
        const float* NW1 = node_w1 + l * 128 * HH;
        const float* NB1 = node_b1 + l * HH;
        const float* NW2 = node_w2 + l * HH * HH;
        const float* NB2 = node_b2 + l * HH;

        const float w128l = W1[128 * HH + lane];
        const float w129l = W1[129 * HH + lane];
        const float b2l   = B2[lane];
        const float cmb   = CMB[lane], ccb = CCB[lane];
        const float cm2l  = CM2[lane], cc2l = CC2[lane];

        // ---- node precompute: Apre = h@W1a + b1, Bpre = h@W1b ----
        for (int i = w; i < PP; i += 4) {
            float a1 = B1[lane];
            float b1v = 0.0f;
            const float4* hr = (const float4*)&sh[i][0];
            for (int k4 = 0; k4 < 16; ++k4) {
                float4 hv = hr[k4];
                int k = k4 * 4;
                a1  += hv.x * W1[(k + 0) * HH + lane] + hv.y * W1[(k + 1) * HH + lane]
                     + hv.z * W1[(k + 2) * HH + lane] + hv.w * W1[(k + 3) * HH + lane];
                b1v += hv.x * W1[(64 + k + 0) * HH + lane] + hv.y * W1[(64 + k + 1) * HH + lane]
                     + hv.z * W1[(64 + k + 2) * HH + lane] + hv.w * W1[(64 + k + 3) * HH + lane];
            }
            sApre[i][lane] = a1;
            sBpre[i][lane] = b1v;
        }
        __syncthreads();

        // ---- edge phase: wave w owns rows a = w, w+4, ... ----
        for (int a = w; a < PP; a += 4) {
            const float ax = sx[a][0], ay = sx[a][1], az = sx[a][2];
            const float apl = sApre[a][lane];

            // E1: z1 = silu(Apre + Bpre + radial*w128 + ea*w129), stored transposed
            for (int e = 0; e < NEDGE; ++e) {
                int b = (e < a) ? e : e + 1;
                float bx = sx[b][0], by = sx[b][1], bz = sx[b][2];
                float dx = ax - bx, dy = ay - by, dz = az - bz;
                float rad = dx * dx + dy * dy + dz * dz;
                float inv = 1.0f / (sqrtf(rad + 1e-8f) + 1.0f);
                float cx = ay * bz - az * by;
                float cy = az * bx - ax * bz;
                float cz = ax * by - ay * bx;
                float cn = 1.0f / (sqrtf(cx * cx + cy * cy + cz * cz + 1e-8f) + 1.0f);
                if (lane < 3) {
                    float cdv = (lane == 0) ? dx : ((lane == 1) ? dy : dz);
                    float crv = (lane == 0) ? cx : ((lane == 1) ? cy : cz);
                    scd[w][e][lane] = cdv * inv;
                    scr[w][e][lane] = crv * cn;
                }
                float z = apl + sBpre[b][lane] + rad * w128l + sea[a][e] * w129l;
                zt[w][lane][e] = silu_f(z);
            }
            WAVE_SYNC();

            // E2: ef = silu(z1 @ W2 + b2)
            float acc[NEDGE];
#pragma unroll
            for (int e = 0; e < NEDGE; ++e) acc[e] = 0.0f;
            for (int k = 0; k < HH; ++k) {
                float wv = W2[k * HH + lane];
                const float* zr = &zt[w][k][0];
                LOAD_ZROW(zr);
                FMA21(acc, wv);
            }
            WAVE_SYNC();
            // silu, segment-sum, store ef transposed (reuse zt)
            float segef = 0.0f;
#pragma unroll
            for (int e = 0; e < NEDGE; ++e) {
                float efv = silu_f(acc[e] + b2l);
                segef += efv;
                zt[w][lane][e] = efv;
            }
            sSegEf[a][lane] = segef;
            WAVE_SYNC();

            // E3: cm1 = ef @ CM1, cc1 = ef @ CC1
            float am[NEDGE], ac[NEDGE];
#pragma unroll
            for (int e = 0; e < NEDGE; ++e) { am[e] = 0.0f; ac[e] = 0.0f; }
            for (int k = 0; k < HH; ++k) {
                float wm = CM1[k * HH + lane];
                float wc = CC1[k * HH + lane];
                const float* zr = &zt[w][k][0];
                LOAD_ZROW(zr);
                FMA21(am, wm);
                FMA21(ac, wc);
            }

            // E4: per-edge scalar cm, cc via wave reduction; accumulate trans
            float tracc = 0.0f;
#pragma unroll
            for (int e = 0; e < NEDGE; ++e) {
                float pm = silu_f(am[e] + cmb) * cm2l;
                float pc = silu_f(ac[e] + ccb) * cc2l;
#pragma unroll
                for (int off = 32; off >= 1; off >>= 1) {
                    pm += __shfl_xor(pm, off);
                    pc += __shfl_xor(pc, off);
                }
                if (lane < 3)
                    tracc += scd[w][e][lane] * pm + pc * scr[w][e][lane];
            }
            if (lane < 3) sTr[a][lane] = tracc;
            WAVE_SYNC();
        }
        __syncthreads();

        // ---- node phase: h += MLP([h, segEf]), x += Tr ----
        for (int i = w; i < PP; i += 4) {
            float m1 = NB1[lane];
            const float4* hr4 = (const float4*)&sh[i][0];
            const float4* sr4 = (const float4*)&sSegEf[i][0];
            for (int k4 = 0; k4 < 16; ++k4) {
                float4 hv = hr4[k4];
                float4 sv = sr4[k4];
                int k = k4 * 4;
                m1 += hv.x * NW1[(k + 0) * HH + lane] + hv.y * NW1[(k + 1) * HH + lane]
                    + hv.z * NW1[(k + 2) * HH + lane] + hv.w * NW1[(k + 3) * HH + lane];
                m1 += sv.x * NW1[(64 + k + 0) * HH + lane] + sv.y * NW1[(64 + k + 1) * HH + lane]
                    + sv.z * NW1[(64 + k + 2) * HH + lane] + sv.w * NW1[(64 + k + 3) * HH + lane];
            }
            float* mb = &zt[w][0][0];  // 64-float wave scratch
            mb[lane] = silu_f(m1);
            WAVE_SYNC();
            float hacc = NB2[lane];
            for (int k4 = 0; k4 < 16; ++k4) {
                float4 mv = *(const float4*)(mb + k4 * 4);
                int k = k4 * 4;
                hacc += mv.x * NW2[(k + 0) * HH + lane] + mv.y * NW2[(k + 1) * HH + lane]
                      + mv.z * NW2[(k + 2) * HH + lane] + mv.w * NW2[(k + 3) * HH + lane];
            }
            WAVE_SYNC();
            sh[i][lane] += hacc;
            if (lane < 3) sx[i][lane] += sTr[i][lane];
        }
        __syncthreads();
    }

    // ---- output: vel = (x - x0) - mean_p(x - x0) ----
    if (tid < 3) {
        float s = 0.0f;
        for (int p = 0; p < PP; ++p) s += sx[p][tid] - sx0[p][tid];
        smean[tid] = s / (float)PP;
    }
    __syncthreads();
    if (tid < PP * 3) {
        int p = tid / 3, d = tid % 3;
        out[g * (PP * 3) + tid] = (sx[p][d] - sx0[p][d]) - smean[d];
    }
}

extern "C" void kernel_launch(void* const* d_in, const int* in_sizes, int n_in,
                              void* d_out, int out_size, void* d_ws, size_t ws_size,
                              hipStream_t stream) {
    const float* input   = (const float*)d_in[0];
    const float* timev   = (const float*)d_in[1];
    const float* emb_w   = (const float*)d_in[2];
    const float* emb_b   = (const float*)d_in[3];
    const float* edge_w1 = (const float*)d_in[4];
    const float* edge_b1 = (const float*)d_in[5];
    const float* edge_w2 = (const float*)d_in[6];
    const float* edge_b2 = (const float*)d_in[7];
    const float* node_w1 = (const float*)d_in[8];
    const float* node_b1 = (const float*)d_in[9];
    const float* node_w2 = (const float*)d_in[10];
    const float* node_b2 = (const float*)d_in[11];
    const float* cm_w1   = (const float*)d_in[12];
    const float* cm_b1   = (const float*)d_in[13];
    const float* cm_w2   = (const float*)d_in[14];
    const float* cc_w1   = (const float*)d_in[15];
    const float* cc_b1   = (const float*)d_in[16];
    const float* cc_w2   = (const float*)d_in[17];
    // d_in[18] = row, d_in[19] = col : edge list is deterministic, recomputed in-kernel

    float* out = (float*)d_out;
    egnn_kernel<<<dim3(1024), dim3(256), 0, stream>>>(
        input, timev, emb_w, emb_b, edge_w1, edge_b1, edge_w2, edge_b2,
        node_w1, node_b1, node_w2, node_b2, cm_w1, cm_b1, cm_w2,
        cc_w1, cc_b1, cc_w2, out);
}

// Round 2
// 913.955 us; speedup vs baseline: 1.7878x; 1.7878x over previous
//
#include <hip/hip_runtime.h>
#include <math.h>

#define PP 22
#define HH 64
#define NL 4
#define NE 462   // 22*21 directed edges per graph

typedef __attribute__((ext_vector_type(8))) short bf16x8;
typedef __attribute__((ext_vector_type(4))) float f32x4;

#define MFMA(A, B, C) __builtin_amdgcn_mfma_f32_16x16x32_bf16(A, B, C, 0, 0, 0)
#define WAVE_SYNC() asm volatile("s_waitcnt lgkmcnt(0)" ::: "memory")

__device__ __forceinline__ float silu_f(float v) { return v / (1.0f + __expf(-v)); }

__device__ __forceinline__ unsigned short f2bf(float x) {
    unsigned int u = __float_as_uint(x);
    u += 0x7fffu + ((u >> 16) & 1u);
    return (unsigned short)(u >> 16);
}
__device__ __forceinline__ float bf2f(unsigned short h) {
    return __uint_as_float(((unsigned int)h) << 16);
}

// ---------------------------------------------------------------------------
// Weight prep: convert W2 / CM1 / CC1 (fp32 64x64 per layer) into hi/lo bf16
// B-fragment blocks for mfma_f32_16x16x32_bf16.
// Block id = ((l*3 + mat)*2 + kt)*4 + nt. Each block = 1024 ushorts:
//   [0..511]   hi frags: lane*8 + j  ->  bf16( M[kt*32 + (lane>>4)*8 + j][nt*16 + (lane&15)] )
//   [512..1023] lo frags (residual)
// ---------------------------------------------------------------------------
__global__ __launch_bounds__(64) void prep_w(const float* __restrict__ w2,
                                             const float* __restrict__ cm1,
                                             const float* __restrict__ cc1,
                                             unsigned short* __restrict__ ws)
{
    int blk = blockIdx.x;
    int nt = blk & 3, kt = (blk >> 2) & 1, mat = (blk >> 3) % 3, l = blk / 24;
    const float* src = (mat == 0 ? w2 : (mat == 1 ? cm1 : cc1)) + l * HH * HH;
    int lane = threadIdx.x;
    int n  = nt * 16 + (lane & 15);
    int kb = kt * 32 + (lane >> 4) * 8;
    unsigned short* dh = ws + blk * 1024 + lane * 8;
    unsigned short* dl = dh + 512;
#pragma unroll
    for (int j = 0; j < 8; ++j) {
        float v = src[(kb + j) * HH + n];
        unsigned short hi = f2bf(v);
        unsigned short lo = f2bf(v - bf2f(hi));
        dh[j] = hi;
        dl[j] = lo;
    }
}

// ---------------------------------------------------------------------------
// Main kernel: one graph per block, 512 threads (8 waves).
// Edge MLPs on MFMA (hi/lo split bf16), everything else fp32 VALU.
// ---------------------------------------------------------------------------
__global__ __launch_bounds__(512, 2) void egnn_kernel(
    const float* __restrict__ input, const float* __restrict__ timev,
    const float* __restrict__ emb_w, const float* __restrict__ emb_b,
    const float* __restrict__ edge_w1, const float* __restrict__ edge_b1,
    const float* __restrict__ edge_b2,
    const float* __restrict__ node_w1, const float* __restrict__ node_b1,
    const float* __restrict__ node_w2, const float* __restrict__ node_b2,
    const float* __restrict__ cm_b1, const float* __restrict__ cm_w2,
    const float* __restrict__ cc_b1, const float* __restrict__ cc_w2,
    const unsigned short* __restrict__ wfr,
    float* __restrict__ out)
{
    const int g    = blockIdx.x;
    const int tid  = threadIdx.x;
    const int w    = tid >> 6;      // wave 0..7
    const int lane = tid & 63;
    const int n0   = lane & 15;
    const int kg   = lane >> 4;     // k-group 0..3

    __shared__ __align__(16) unsigned short wlds[24 * 1024]; // 48KB frag blocks
    __shared__ float sApre[PP][68];
    __shared__ float sBpre[PP][68];
    __shared__ float sh[PP][HH];
    __shared__ float sSeg[PP][HH];
    __shared__ float sx[PP][3], sx0[PP][3], sTr[PP][3];
    __shared__ float srad[NE], sea[NE];
    __shared__ float scd[NE][3], scr[NE][3];
    __shared__ __align__(16) unsigned int sEF[8][1024];      // per-wave EF tile (hi|lo packed)
    __shared__ float sW128[HH], sW129[HH];
    __shared__ float smean[3];

    // ---- init coords + h ----
    if (tid < PP * 3) {
        float v = input[g * (PP * 3) + tid];
        sx0[tid / 3][tid % 3] = v;
        sx [tid / 3][tid % 3] = v;
    }
    {
        float tg = timev[g];
        for (int i = w; i < PP; i += 8)
            sh[i][lane] = emb_w[i * HH + lane] + tg * emb_w[PP * HH + lane] + emb_b[lane];
    }
    __syncthreads();
    // ---- edge_attr (fixed, from x0) ----
    if (tid < NE) {
        int a = tid / 21, r = tid % 21;
        int b = (r < a) ? r : r + 1;
        float dx = sx0[a][0] - sx0[b][0];
        float dy = sx0[a][1] - sx0[b][1];
        float dz = sx0[a][2] - sx0[b][2];
        sea[tid] = dx * dx + dy * dy + dz * dz;
    }

    for (int l = 0; l < NL; ++l) {
        __syncthreads();
        // ---- stage weight frags for this layer (48KB) ----
        {
            const uint4* src = (const uint4*)(wfr + (size_t)l * 24576);
            uint4* dst = (uint4*)wlds;
            for (int idx = tid; idx < 3072; idx += 512) dst[idx] = src[idx];
        }
        if (tid < HH)            sW128[tid]      = edge_w1[(l * 130 + 128) * HH + tid];
        else if (tid < 2 * HH)   sW129[tid - HH] = edge_w1[(l * 130 + 129) * HH + tid - HH];
        // ---- geometry from current x ----
        if (tid < NE) {
            int a = tid / 21, r = tid % 21;
            int b = (r < a) ? r : r + 1;
            float ax = sx[a][0], ay = sx[a][1], az = sx[a][2];
            float bx = sx[b][0], by = sx[b][1], bz = sx[b][2];
            float dx = ax - bx, dy = ay - by, dz = az - bz;
            float rad = dx * dx + dy * dy + dz * dz;
            srad[tid] = rad;
            float inv = 1.0f / (sqrtf(rad + 1e-8f) + 1.0f);
            scd[tid][0] = dx * inv; scd[tid][1] = dy * inv; scd[tid][2] = dz * inv;
            float cx = ay * bz - az * by;
            float cy = az * bx - ax * bz;
            float cz = ax * by - ay * bx;
            float cn = 1.0f / (sqrtf(cx * cx + cy * cy + cz * cz + 1e-8f) + 1.0f);
            scr[tid][0] = cx * cn; scr[tid][1] = cy * cn; scr[tid][2] = cz * cn;
        }
        // ---- Apre/Bpre: h @ W1[0:64] (+b1), h @ W1[64:128] ----
        {
            const float* W1 = edge_w1 + l * 130 * HH;
            const float* B1 = edge_b1 + l * HH;
            for (int i = w; i < PP; i += 8) {
                float a1 = B1[lane];
                float b1v = 0.0f;
                const float4* hr = (const float4*)&sh[i][0];
#pragma unroll 4
                for (int k4 = 0; k4 < 16; ++k4) {
                    float4 hv = hr[k4];
                    int k = k4 * 4;
                    a1  += hv.x * W1[(k + 0) * HH + lane] + hv.y * W1[(k + 1) * HH + lane]
                         + hv.z * W1[(k + 2) * HH + lane] + hv.w * W1[(k + 3) * HH + lane];
                    b1v += hv.x * W1[(64 + k + 0) * HH + lane] + hv.y * W1[(64 + k + 1) * HH + lane]
                         + hv.z * W1[(64 + k + 2) * HH + lane] + hv.w * W1[(64 + k + 3) * HH + lane];
                }
                sApre[i][lane] = a1;
                sBpre[i][lane] = b1v;
            }
        }
        // per-lane layer constants (n = nt*16 + n0)
        float b2r[4], cmbr[4], ccbr[4], cm2r[4], cc2r[4];
#pragma unroll
        for (int nt = 0; nt < 4; ++nt) {
            int idx = l * HH + nt * 16 + n0;
            b2r[nt]  = edge_b2[idx];
            cmbr[nt] = cm_b1[idx];
            ccbr[nt] = cc_b1[idx];
            cm2r[nt] = cm_w2[idx];
            cc2r[nt] = cc_w2[idx];
        }
        __syncthreads();

        // ================= edge phase: wave w owns nodes a = w, w+8, ... ======
        for (int a = w; a < PP; a += 8) {
            float seg[4] = {0.f, 0.f, 0.f, 0.f};
            float trl = 0.0f;   // lane n0<3 accumulates trans[d=n0]

#pragma unroll
            for (int t = 0; t < 2; ++t) {
                // ---- A-frags: z1 = silu(Apre[a] + Bpre[b] + rad*w128 + ea*w129)
                int e  = t * 16 + n0;             // A-frag row = edge slot
                int ok = (e < 21);
                int b  = ok ? ((e < a) ? e : e + 1) : a;
                int ge = a * 21 + (ok ? e : 0);
                float radv = ok ? srad[ge] : 0.f;
                float eav  = ok ? sea[ge]  : 0.f;

                bf16x8 ahi[2], alo[2];
#pragma unroll
                for (int kt = 0; kt < 2; ++kt) {
                    int kb = kt * 32 + kg * 8;
                    const float* ap  = &sApre[a][kb];
                    const float* bp  = &sBpre[b][kb];
                    const float* w8p = &sW128[kb];
                    const float* w9p = &sW129[kb];
#pragma unroll
                    for (int j = 0; j < 8; ++j) {
                        float z = ap[j] + bp[j] + radv * w8p[j] + eav * w9p[j];
                        z = silu_f(z);
                        unsigned short hi = f2bf(z);
                        unsigned short lo = f2bf(z - bf2f(hi));
                        ahi[kt][j] = (short)hi;
                        alo[kt][j] = (short)lo;
                    }
                }

                // ---- E2: EF = silu(z1 @ W2 + b2)  (3-mfma split) ----
                f32x4 acc[4];
#pragma unroll
                for (int nt = 0; nt < 4; ++nt) acc[nt] = (f32x4){0.f, 0.f, 0.f, 0.f};
#pragma unroll
                for (int nt = 0; nt < 4; ++nt) {
#pragma unroll
                    for (int kt = 0; kt < 2; ++kt) {
                        int fb = (kt * 4 + nt) * 1024;           // mat 0
                        bf16x8 bhi = *(const bf16x8*)&wlds[fb + lane * 8];
                        bf16x8 blo = *(const bf16x8*)&wlds[fb + 512 + lane * 8];
                        acc[nt] = MFMA(ahi[kt], bhi, acc[nt]);
                        acc[nt] = MFMA(alo[kt], bhi, acc[nt]);
                        acc[nt] = MFMA(ahi[kt], blo, acc[nt]);
                    }
                }

                // ---- silu + mask pads + seg partial + split/pack to sEF ----
#pragma unroll
                for (int nt = 0; nt < 4; ++nt) {
#pragma unroll
                    for (int r = 0; r < 4; ++r) {
                        int row = kg * 4 + r;                    // C-frag row
                        float v = silu_f(acc[nt][r] + b2r[nt]);
                        if (t * 16 + row >= 21) v = 0.f;
                        seg[nt] += v;
                        unsigned short hi = f2bf(v);
                        unsigned short lo = f2bf(v - bf2f(hi));
                        int col = (nt * 16 + n0) ^ ((row & 7) << 3);
                        sEF[w][row * 64 + col] = (unsigned int)hi | ((unsigned int)lo << 16);
                    }
                }
                WAVE_SYNC();

                // ---- E3 A-frags from sEF ----
                bf16x8 ehi[2], elo[2];
#pragma unroll
                for (int kt = 0; kt < 2; ++kt) {
                    int cb = (kt * 32 + kg * 8) ^ ((n0 & 7) << 3);
                    const unsigned int* p = &sEF[w][n0 * 64 + cb];
                    uint4 u0 = *(const uint4*)p;
                    uint4 u1 = *(const uint4*)(p + 4);
                    unsigned int uu[8] = {u0.x, u0.y, u0.z, u0.w, u1.x, u1.y, u1.z, u1.w};
#pragma unroll
                    for (int j = 0; j < 8; ++j) {
                        ehi[kt][j] = (short)(uu[j] & 0xffffu);
                        elo[kt][j] = (short)(uu[j] >> 16);
                    }
                }
                WAVE_SYNC();

                // ---- E3: cm1 = EF @ CM1, cc1 = EF @ CC1 ----
                f32x4 am[4], ac[4];
#pragma unroll
                for (int nt = 0; nt < 4; ++nt) {
                    am[nt] = (f32x4){0.f, 0.f, 0.f, 0.f};
                    ac[nt] = (f32x4){0.f, 0.f, 0.f, 0.f};
                }
#pragma unroll
                for (int nt = 0; nt < 4; ++nt) {
#pragma unroll
                    for (int kt = 0; kt < 2; ++kt) {
                        int fbm = ((2 + kt) * 4 + nt) * 1024;    // mat 1 (CM1)
                        int fbc = ((4 + kt) * 4 + nt) * 1024;    // mat 2 (CC1)
                        bf16x8 mhi = *(const bf16x8*)&wlds[fbm + lane * 8];
                        bf16x8 mlo = *(const bf16x8*)&wlds[fbm + 512 + lane * 8];
                        bf16x8 chi = *(const bf16x8*)&wlds[fbc + lane * 8];
                        bf16x8 clo = *(const bf16x8*)&wlds[fbc + 512 + lane * 8];
                        am[nt] = MFMA(ehi[kt], mhi, am[nt]);
                        am[nt] = MFMA(elo[kt], mhi, am[nt]);
                        am[nt] = MFMA(ehi[kt], mlo, am[nt]);
                        ac[nt] = MFMA(ehi[kt], chi, ac[nt]);
                        ac[nt] = MFMA(elo[kt], chi, ac[nt]);
                        ac[nt] = MFMA(ehi[kt], clo, ac[nt]);
                    }
                }

                // ---- cm/cc scalars + trans accumulation ----
#pragma unroll
                for (int r = 0; r < 4; ++r) {
                    float pm = 0.f, pc = 0.f;
#pragma unroll
                    for (int nt = 0; nt < 4; ++nt) {
                        pm += silu_f(am[nt][r] + cmbr[nt]) * cm2r[nt];
                        pc += silu_f(ac[nt][r] + ccbr[nt]) * cc2r[nt];
                    }
#pragma unroll
                    for (int off = 1; off <= 8; off <<= 1) {
                        pm += __shfl_xor(pm, off);
                        pc += __shfl_xor(pc, off);
                    }
                    int erow = t * 16 + kg * 4 + r;
                    if (erow < 21 && n0 < 3) {
                        int ge2 = a * 21 + erow;
                        trl += scd[ge2][n0] * pm + pc * scr[ge2][n0];
                    }
                }
            } // t

            // ---- finalize node: column sums + coord update ----
#pragma unroll
            for (int nt = 0; nt < 4; ++nt) {
                seg[nt] += __shfl_xor(seg[nt], 16);
                seg[nt] += __shfl_xor(seg[nt], 32);
            }
            trl += __shfl_xor(trl, 16);
            trl += __shfl_xor(trl, 32);
            if (lane < 16) {
#pragma unroll
                for (int nt = 0; nt < 4; ++nt) sSeg[a][nt * 16 + lane] = seg[nt];
            }
            if (lane < 3) sTr[a][lane] = trl;
        } // a
        __syncthreads();

        // ================= node phase: h += MLP([h, segEf]), x += Tr =========
        {
            const float* NW1 = node_w1 + l * 128 * HH;
            const float* NB1 = node_b1 + l * HH;
            const float* NW2 = node_w2 + l * HH * HH;
            const float* NB2 = node_b2 + l * HH;
            for (int i = w; i < PP; i += 8) {
                float m1 = NB1[lane];
                const float4* hr4 = (const float4*)&sh[i][0];
                const float4* sr4 = (const float4*)&sSeg[i][0];
#pragma unroll 4
                for (int k4 = 0; k4 < 16; ++k4) {
                    float4 hv = hr4[k4];
                    float4 sv = sr4[k4];
                    int k = k4 * 4;
                    m1 += hv.x * NW1[(k + 0) * HH + lane] + hv.y * NW1[(k + 1) * HH + lane]
                        + hv.z * NW1[(k + 2) * HH + lane] + hv.w * NW1[(k + 3) * HH + lane];
                    m1 += sv.x * NW1[(64 + k + 0) * HH + lane] + sv.y * NW1[(64 + k + 1) * HH + lane]
                        + sv.z * NW1[(64 + k + 2) * HH + lane] + sv.w * NW1[(64 + k + 3) * HH + lane];
                }
                float* mb = (float*)&sEF[w][0];   // per-wave 64-float scratch
                mb[lane] = silu_f(m1);
                WAVE_SYNC();
                float hacc = NB2[lane];
#pragma unroll 4
                for (int k4 = 0; k4 < 16; ++k4) {
                    float4 mv = *(const float4*)(mb + k4 * 4);
                    int k = k4 * 4;
                    hacc += mv.x * NW2[(k + 0) * HH + lane] + mv.y * NW2[(k + 1) * HH + lane]
                          + mv.z * NW2[(k + 2) * HH + lane] + mv.w * NW2[(k + 3) * HH + lane];
                }
                WAVE_SYNC();
                sh[i][lane] += hacc;
                if (lane < 3) sx[i][lane] += sTr[i][lane];
            }
        }
    } // layers

    __syncthreads();
    // ---- output: vel = (x - x0) - mean_p(x - x0) ----
    if (tid < 3) {
        float s = 0.0f;
        for (int p = 0; p < PP; ++p) s += sx[p][tid] - sx0[p][tid];
        smean[tid] = s / (float)PP;
    }
    __syncthreads();
    if (tid < PP * 3) {
        int p = tid / 3, d = tid % 3;
        out[g * (PP * 3) + tid] = (sx[p][d] - sx0[p][d]) - smean[d];
    }
}

extern "C" void kernel_launch(void* const* d_in, const int* in_sizes, int n_in,
                              void* d_out, int out_size, void* d_ws, size_t ws_size,
                              hipStream_t stream) {
    const float* input   = (const float*)d_in[0];
    const float* timev   = (const float*)d_in[1];
    const float* emb_w   = (const float*)d_in[2];
    const float* emb_b   = (const float*)d_in[3];
    const float* edge_w1 = (const float*)d_in[4];
    const float* edge_b1 = (const float*)d_in[5];
    const float* edge_w2 = (const float*)d_in[6];
    const float* edge_b2 = (const float*)d_in[7];
    const float* node_w1 = (const float*)d_in[8];
    const float* node_b1 = (const float*)d_in[9];
    const float* node_w2 = (const float*)d_in[10];
    const float* node_b2 = (const float*)d_in[11];
    const float* cm_w1   = (const float*)d_in[12];
    const float* cm_b1   = (const float*)d_in[13];
    const float* cm_w2   = (const float*)d_in[14];
    const float* cc_w1   = (const float*)d_in[15];
    const float* cc_b1   = (const float*)d_in[16];
    const float* cc_w2   = (const float*)d_in[17];
    // d_in[18]=row, d_in[19]=col: deterministic fully-connected edges, recomputed in-kernel

    unsigned short* wsu = (unsigned short*)d_ws;
    prep_w<<<dim3(96), dim3(64), 0, stream>>>(edge_w2, cm_w1, cc_w1, wsu);

    float* out = (float*)d_out;
    egnn_kernel<<<dim3(1024), dim3(512), 0, stream>>>(
        input, timev, emb_w, emb_b, edge_w1, edge_b1, edge_b2,
        node_w1, node_b1, node_w2, node_b2, cm_b1, cm_w2, cc_b1, cc_w2,
        wsu, out);
}